// Round 16
// baseline (39.078 us; speedup 1.0000x reference)
//
#include <hip/hip_runtime.h>
#include <math.h>

typedef unsigned long long u64;
typedef unsigned int u32;

#define NB   2
#define L0   4800
#define L1   4800
#define H1C  60
#define W1C  80
#define ROWS 32
#define RPB  (L0 / ROWS)          // 150 row-groups per batch
#define NBLK (NB * RPB)           // 300 blocks
#define NT   256                  // 4 waves (champion geometry)
#define NW   (NT / 64)
#define L14  (L1 / 2)             // 2400 float4 per batch
// partials layout: k in [0,12): {Sm,Sl2,Ssl2,Ss,Sv,Ssq} x {word-mask, byte-mask}

// ---------------------------------------------------------------------------
// Round 16 -- continue the only live lever (fewer, fatter blocks):
// ROWS 24->32, NBLK 400->300. Each pt1 float4 serves 32 rows; per-block
// fixed cost paid 300x. State ~160-175 VGPR -> __launch_bounds__(256,2)
// (cap 256, definitively spill-free). The 2-wave/SIMD bound is costless:
// grid supplies only ~1.2 blocks/CU (~4.7 waves/CU) anyway.
// Everything else identical to the r15 champion: direct-L2 stream,
// u64-packed reduce, 32-lane epilogue, split finalize, parity XCD swizzle.
// Ladder: NBLK 1200->600->400->300 = 39.4 -> 36.8 -> 35.4 -> ? us.
// ---------------------------------------------------------------------------
__global__ __launch_bounds__(NT, 2) void s2ld_main(
    const float* __restrict__ w_pt0,    // [NB][L0][2]
    const float* __restrict__ pt1,      // [NB][L1][2]
    const void*  __restrict__ maskp,    // [NB][L0] word- or byte-bool
    const float* __restrict__ score0,   // [NB][L0]
    const float* __restrict__ score1,   // [NB][L1]
    const float* __restrict__ scale0,   // [NB][2]
    const float* __restrict__ scale1,   // [NB][2]
    float*       __restrict__ partials) // [12][NBLK]
{
    __shared__ u64 redk[ROWS * NW];     // 1024 B -- only LDS in the kernel

    const int tid  = threadIdx.x;
    const int blk  = blockIdx.x;
    // parity swizzle: stride-8 XCD round-robin keeps each XCD on one batch's pt1
    const int n    = blk & 1;
    const int rg   = blk >> 1;          // row-group within batch, 0..149
    const int gi0  = n * L0 + rg * ROWS;
    const int lane = tid & 63;
    const int wv   = tid >> 6;

    const float4* p1 = (const float4*)(pt1 + (size_t)n * L1 * 2);
    const float4* p0 = (const float4*)(w_pt0 + (size_t)gi0 * 2);  // 16 float4

    // minimize s_j = |q_j|^2 - 2 p.q_j (same order as d2); ax=-2px, ay=-2py.
    float ax[ROWS], ay[ROWS];
    #pragma unroll
    for (int h = 0; h < ROWS / 2; ++h) {
        float4 f = p0[h];
        ax[2*h]   = -2.0f * f.x; ay[2*h]   = -2.0f * f.y;
        ax[2*h+1] = -2.0f * f.z; ay[2*h+1] = -2.0f * f.w;
    }
    float bd[ROWS]; int bj[ROWS];
    #pragma unroll
    for (int r = 0; r < ROWS; ++r) { bd[r] = 3.0e38f; bj[r] = 0; }

    // direct-L2 stream over pt1; each float4 serves all 32 rows. j ascends
    // per thread => first-occurrence argmin within a thread; cross-thread
    // ties resolved in the u64 reduce.
    for (int j4 = tid; j4 < L14; j4 += NT) {
        const float4 q = p1[j4];
        const float c0 = fmaf(q.x, q.x, q.y * q.y);
        const float c1 = fmaf(q.z, q.z, q.w * q.w);
        const int j0 = 2 * j4;
        #pragma unroll
        for (int r = 0; r < ROWS; ++r) {
            float s0 = fmaf(ax[r], q.x, fmaf(ay[r], q.y, c0));
            if (s0 < bd[r]) { bd[r] = s0; bj[r] = j0; }
            float s1 = fmaf(ax[r], q.z, fmaf(ay[r], q.w, c1));
            if (s1 < bd[r]) { bd[r] = s1; bj[r] = j0 + 1; }
        }
    }

    // pack (monotone-transformed s, j) into u64: min_u64 == (min s, then min j)
    #pragma unroll
    for (int r = 0; r < ROWS; ++r) {
        u32 b = __float_as_uint(bd[r]);
        u32 t = b ^ ((u32)((int)b >> 31) | 0x80000000u);   // IEEE->monotone u32
        u64 key = ((u64)t << 32) | (u32)bj[r];
        #pragma unroll
        for (int off = 32; off; off >>= 1) {
            u64 ok = __shfl_xor(key, off);
            if (ok < key) key = ok;
        }
        if (lane == 0) redk[r * NW + wv] = key;
    }
    __syncthreads();                    // the kernel's only barrier

    // parallel epilogue: lanes 0..31 (wave 0), one row each -- exactly ROWS.
    if (tid < 32) {
        const int r = tid;
        u64 key = redk[r * NW + 0];
        #pragma unroll
        for (int w = 1; w < NW; ++w) {
            u64 ok = redk[r * NW + w];
            if (ok < key) key = ok;
        }
        const int jj = (int)(u32)key;
        const int gi = gi0 + r;
        const float2 qp = ((const float2*)w_pt0)[gi];
        const float2 qn = ((const float2*)(pt1 + (size_t)n * L1 * 2))[jj];
        const float dx = qp.x - qn.x, dy = qp.y - qn.y;
        const float l2 = sqrtf(dx * dx + dy * dy);         // exact d2

        const float thr = 8.0f * scale0[n * 2 + 0];
        const float sxd = ((float)W1C * scale1[n * 2 + 0] * 8.0f - 1.0f) * 0.5f;
        const float syd = ((float)H1C * scale1[n * 2 + 1] * 8.0f - 1.0f) * 0.5f;
        const float* im = score1 + (size_t)n * L1;

        // both mask interpretations (int32/float32 agree on word != 0)
        const float mw = (((const u32*)maskp)[gi] != 0u) ? 1.0f : 0.0f;
        const float mb = (((const unsigned char*)maskp)[gi] != 0) ? 1.0f : 0.0f;
        const float inthr = (l2 <= thr) ? 1.0f : 0.0f;

        const float s0v  = score0[gi];
        const float ssum = im[jj] + s0v;

        // bilinear grid-sample of score1 as 60x80 image, zeros outside
        const float gx = (qp.x / sxd) * 0.5f * (float)(W1C - 1);
        const float gy = (qp.y / syd) * 0.5f * (float)(H1C - 1);
        const float x0 = floorf(gx), y0 = floorf(gy);
        const float x1 = x0 + 1.0f,  y1 = y0 + 1.0f;
        const float wx1 = gx - x0, wx0 = 1.0f - wx1;
        const float wy1 = gy - y0, wy0 = 1.0f - wy1;

        auto corner = [&](float xf, float yf) -> float {
            bool inb = (xf >= 0.0f) && (xf <= (float)(W1C - 1)) &&
                       (yf >= 0.0f) && (yf <= (float)(H1C - 1));
            int xc = (int)fminf(fmaxf(xf, 0.0f), (float)(W1C - 1));
            int yc = (int)fminf(fmaxf(yf, 0.0f), (float)(H1C - 1));
            float v = im[yc * W1C + xc];
            return inb ? v : 0.0f;
        };
        const float res = corner(x0, y0) * wx0 * wy0
                        + corner(x1, y0) * wx1 * wy0
                        + corner(x0, y1) * wx0 * wy1
                        + corner(x1, y1) * wx1 * wy1;
        const float dsc = res - s0v;
        const float dsq = dsc * dsc;

        const float dvw = inthr * mw, dvb = inthr * mb;
        float v0  = dvw,        v1 = l2 * dvw,  v2  = ssum * l2 * dvw;
        float v3  = ssum * dvw, v4 = mw,        v5  = dsq * mw;
        float v6  = dvb,        v7 = l2 * dvb,  v8  = ssum * l2 * dvb;
        float v9  = ssum * dvb, v10 = mb,       v11 = dsq * mb;
#define RED32(V) { V += __shfl_xor(V, 16); V += __shfl_xor(V, 8); \
                   V += __shfl_xor(V, 4);  V += __shfl_xor(V, 2); \
                   V += __shfl_xor(V, 1); }
        RED32(v0) RED32(v1) RED32(v2) RED32(v3) RED32(v4)  RED32(v5)
        RED32(v6) RED32(v7) RED32(v8) RED32(v9) RED32(v10) RED32(v11)
#undef RED32
        if (tid == 0) {
            partials[ 0 * NBLK + blk] = v0;  partials[ 1 * NBLK + blk] = v1;
            partials[ 2 * NBLK + blk] = v2;  partials[ 3 * NBLK + blk] = v3;
            partials[ 4 * NBLK + blk] = v4;  partials[ 5 * NBLK + blk] = v5;
            partials[ 6 * NBLK + blk] = v6;  partials[ 7 * NBLK + blk] = v7;
            partials[ 8 * NBLK + blk] = v8;  partials[ 9 * NBLK + blk] = v9;
            partials[10 * NBLK + blk] = v10; partials[11 * NBLK + blk] = v11;
        }
    }
}

// ---------------------------------------------------------------------------
// Finalize: one block. Detects mask format, reduces 12 partial arrays, emits.
// ---------------------------------------------------------------------------
__global__ __launch_bounds__(NT) void s2ld_finalize(
    const float* __restrict__ partials,
    const void*  __restrict__ maskp,
    float*       __restrict__ out)
{
    __shared__ float fin[12 * NW];
    __shared__ u32   sbad;

    const int tid  = threadIdx.x;
    const int lane = tid & 63;
    const int wv   = tid >> 6;

    if (tid == 0) sbad = 0u;
    __syncthreads();
    {
        // mask format detection (first 2400 words in-bounds for all layouts)
        u32 bad = 0u;
        const u32* mwp = (const u32*)maskp;
        for (int i = tid; i < 2400; i += NT) {
            u32 w = mwp[i];
            if (w != 0u && w != 1u && w != 0x3f800000u) bad = 1u;
        }
        atomicOr(&sbad, bad);
    }

    for (int k = 0; k < 12; ++k) {
        float s = 0.0f;
        for (int rbl = tid; rbl < NBLK; rbl += NT) s += partials[k * NBLK + rbl];
        #pragma unroll
        for (int off = 32; off; off >>= 1) s += __shfl_xor(s, off);
        if (lane == 0) fin[k * NW + wv] = s;
    }
    __syncthreads();

    if (tid == 0) {
        const int o = (sbad == 0u) ? 0 : 6;   // word-format vs byte-format
        float S[6];
        #pragma unroll
        for (int k = 0; k < 6; ++k) {
            float s = 0.0f;
            #pragma unroll
            for (int w = 0; w < NW; ++w) s += fin[(o + k) * NW + w];
            S[k] = s;
        }
        const float den = fmaxf(S[0], 1.0f);
        const float lm  = S[1] / den;
        out[0] = lm;                              // loc_loss_mean
        out[1] = (S[2] - lm * S[3]) / den;        // rep_loss_mean
        out[2] = 2.0f * S[5] / fmaxf(S[4], 1.0f); // score_loss
    }
}

extern "C" void kernel_launch(void* const* d_in, const int* in_sizes, int n_in,
                              void* d_out, int out_size, void* d_ws, size_t ws_size,
                              hipStream_t stream) {
    const float* w_pt0  = (const float*)d_in[0];
    const float* pt1    = (const float*)d_in[1];
    const void*  maskp  =               d_in[2];
    const float* score0 = (const float*)d_in[3];
    const float* score1 = (const float*)d_in[4];
    // d_in[5] = image1 (zeros) -- unused
    const float* scale0 = (const float*)d_in[6];
    const float* scale1 = (const float*)d_in[7];

    float* partials = (float*)d_ws;   // 12 * 300 * 4 B, fully rewritten

    s2ld_main<<<NBLK, NT, 0, stream>>>(w_pt0, pt1, maskp, score0, score1,
                                       scale0, scale1, partials);
    s2ld_finalize<<<1, NT, 0, stream>>>(partials, maskp, (float*)d_out);
}

// Round 17
// 34.864 us; speedup vs baseline: 1.1209x; 1.1209x over previous
//
#include <hip/hip_runtime.h>
#include <math.h>

typedef unsigned long long u64;
typedef unsigned int u32;

#define NB   2
#define L0   4800
#define L1   4800
#define H1C  60
#define W1C  80
#define ROWS 24
#define RPB  (L0 / ROWS)          // 200 row-groups per batch
#define NBLK (NB * RPB)           // 400 blocks
#define NT   256                  // 4 waves (champion geometry)
#define NW   (NT / 64)
#define L14  (L1 / 2)             // 2400 float4 per batch
// partials layout: k in [0,12): {Sm,Sl2,Ssl2,Ss,Sv,Ssq} x {word-mask, byte-mask}

// ---------------------------------------------------------------------------
// Round 17 -- exact revert to the r15 champion (35.4us), the measured optimum
// of the block-count ladder: NBLK 1200->600->400->300 = 39.4/36.8/35.4/39.1.
// ROWS=24 per block, each pt1 float4 serves 24 rows; direct-L2 stream (LDS
// staging proven equal, r10 vs r11); u64-packed (min s, then min j) reduce;
// 32-lane epilogue (24 active); split finalize (fused atomic tail cost ~3us,
// r8 vs r9); parity XCD swizzle. (256,3): cap ~168 VGPR, spill-free.
// ---------------------------------------------------------------------------
__global__ __launch_bounds__(NT, 3) void s2ld_main(
    const float* __restrict__ w_pt0,    // [NB][L0][2]
    const float* __restrict__ pt1,      // [NB][L1][2]
    const void*  __restrict__ maskp,    // [NB][L0] word- or byte-bool
    const float* __restrict__ score0,   // [NB][L0]
    const float* __restrict__ score1,   // [NB][L1]
    const float* __restrict__ scale0,   // [NB][2]
    const float* __restrict__ scale1,   // [NB][2]
    float*       __restrict__ partials) // [12][NBLK]
{
    __shared__ u64 redk[ROWS * NW];     // 768 B -- only LDS in the kernel

    const int tid  = threadIdx.x;
    const int blk  = blockIdx.x;
    // parity swizzle: stride-8 XCD round-robin keeps each XCD on one batch's pt1
    const int n    = blk & 1;
    const int rg   = blk >> 1;          // row-group within batch, 0..199
    const int gi0  = n * L0 + rg * ROWS;
    const int lane = tid & 63;
    const int wv   = tid >> 6;

    const float4* p1 = (const float4*)(pt1 + (size_t)n * L1 * 2);
    const float4* p0 = (const float4*)(w_pt0 + (size_t)gi0 * 2);  // 12 float4

    // minimize s_j = |q_j|^2 - 2 p.q_j (same order as d2); ax=-2px, ay=-2py.
    float ax[ROWS], ay[ROWS];
    #pragma unroll
    for (int h = 0; h < ROWS / 2; ++h) {
        float4 f = p0[h];
        ax[2*h]   = -2.0f * f.x; ay[2*h]   = -2.0f * f.y;
        ax[2*h+1] = -2.0f * f.z; ay[2*h+1] = -2.0f * f.w;
    }
    float bd[ROWS]; int bj[ROWS];
    #pragma unroll
    for (int r = 0; r < ROWS; ++r) { bd[r] = 3.0e38f; bj[r] = 0; }

    // direct-L2 stream over pt1; each float4 serves all 24 rows. j ascends
    // per thread => first-occurrence argmin within a thread; cross-thread
    // ties resolved in the u64 reduce.
    for (int j4 = tid; j4 < L14; j4 += NT) {
        const float4 q = p1[j4];
        const float c0 = fmaf(q.x, q.x, q.y * q.y);
        const float c1 = fmaf(q.z, q.z, q.w * q.w);
        const int j0 = 2 * j4;
        #pragma unroll
        for (int r = 0; r < ROWS; ++r) {
            float s0 = fmaf(ax[r], q.x, fmaf(ay[r], q.y, c0));
            if (s0 < bd[r]) { bd[r] = s0; bj[r] = j0; }
            float s1 = fmaf(ax[r], q.z, fmaf(ay[r], q.w, c1));
            if (s1 < bd[r]) { bd[r] = s1; bj[r] = j0 + 1; }
        }
    }

    // pack (monotone-transformed s, j) into u64: min_u64 == (min s, then min j)
    #pragma unroll
    for (int r = 0; r < ROWS; ++r) {
        u32 b = __float_as_uint(bd[r]);
        u32 t = b ^ ((u32)((int)b >> 31) | 0x80000000u);   // IEEE->monotone u32
        u64 key = ((u64)t << 32) | (u32)bj[r];
        #pragma unroll
        for (int off = 32; off; off >>= 1) {
            u64 ok = __shfl_xor(key, off);
            if (ok < key) key = ok;
        }
        if (lane == 0) redk[r * NW + wv] = key;
    }
    __syncthreads();                    // the kernel's only barrier

    // parallel epilogue: lanes 0..31 (wave 0); rows >= ROWS contribute zeros
    // so the 32-lane shfl reduction tree stays uniform.
    if (tid < 32) {
        const int r = tid;
        const bool active = (r < ROWS);
        float v0=0,v1=0,v2=0,v3=0,v4=0,v5=0,v6=0,v7=0,v8=0,v9=0,v10=0,v11=0;
        if (active) {
            u64 key = redk[r * NW + 0];
            #pragma unroll
            for (int w = 1; w < NW; ++w) {
                u64 ok = redk[r * NW + w];
                if (ok < key) key = ok;
            }
            const int jj = (int)(u32)key;
            const int gi = gi0 + r;
            const float2 qp = ((const float2*)w_pt0)[gi];
            const float2 qn = ((const float2*)(pt1 + (size_t)n * L1 * 2))[jj];
            const float dx = qp.x - qn.x, dy = qp.y - qn.y;
            const float l2 = sqrtf(dx * dx + dy * dy);     // exact d2

            const float thr = 8.0f * scale0[n * 2 + 0];
            const float sxd = ((float)W1C * scale1[n * 2 + 0] * 8.0f - 1.0f) * 0.5f;
            const float syd = ((float)H1C * scale1[n * 2 + 1] * 8.0f - 1.0f) * 0.5f;
            const float* im = score1 + (size_t)n * L1;

            // both mask interpretations (int32/float32 agree on word != 0)
            const float mw = (((const u32*)maskp)[gi] != 0u) ? 1.0f : 0.0f;
            const float mb = (((const unsigned char*)maskp)[gi] != 0) ? 1.0f : 0.0f;
            const float inthr = (l2 <= thr) ? 1.0f : 0.0f;

            const float s0v  = score0[gi];
            const float ssum = im[jj] + s0v;

            // bilinear grid-sample of score1 as 60x80 image, zeros outside
            const float gx = (qp.x / sxd) * 0.5f * (float)(W1C - 1);
            const float gy = (qp.y / syd) * 0.5f * (float)(H1C - 1);
            const float x0 = floorf(gx), y0 = floorf(gy);
            const float x1 = x0 + 1.0f,  y1 = y0 + 1.0f;
            const float wx1 = gx - x0, wx0 = 1.0f - wx1;
            const float wy1 = gy - y0, wy0 = 1.0f - wy1;

            auto corner = [&](float xf, float yf) -> float {
                bool inb = (xf >= 0.0f) && (xf <= (float)(W1C - 1)) &&
                           (yf >= 0.0f) && (yf <= (float)(H1C - 1));
                int xc = (int)fminf(fmaxf(xf, 0.0f), (float)(W1C - 1));
                int yc = (int)fminf(fmaxf(yf, 0.0f), (float)(H1C - 1));
                float v = im[yc * W1C + xc];
                return inb ? v : 0.0f;
            };
            const float res = corner(x0, y0) * wx0 * wy0
                            + corner(x1, y0) * wx1 * wy0
                            + corner(x0, y1) * wx0 * wy1
                            + corner(x1, y1) * wx1 * wy1;
            const float dsc = res - s0v;
            const float dsq = dsc * dsc;

            const float dvw = inthr * mw, dvb = inthr * mb;
            v0 = dvw;         v1 = l2 * dvw;   v2  = ssum * l2 * dvw;
            v3 = ssum * dvw;  v4 = mw;         v5  = dsq * mw;
            v6 = dvb;         v7 = l2 * dvb;   v8  = ssum * l2 * dvb;
            v9 = ssum * dvb;  v10 = mb;        v11 = dsq * mb;
        }
#define RED32(V) { V += __shfl_xor(V, 16); V += __shfl_xor(V, 8); \
                   V += __shfl_xor(V, 4);  V += __shfl_xor(V, 2); \
                   V += __shfl_xor(V, 1); }
        RED32(v0) RED32(v1) RED32(v2) RED32(v3) RED32(v4)  RED32(v5)
        RED32(v6) RED32(v7) RED32(v8) RED32(v9) RED32(v10) RED32(v11)
#undef RED32
        if (tid == 0) {
            partials[ 0 * NBLK + blk] = v0;  partials[ 1 * NBLK + blk] = v1;
            partials[ 2 * NBLK + blk] = v2;  partials[ 3 * NBLK + blk] = v3;
            partials[ 4 * NBLK + blk] = v4;  partials[ 5 * NBLK + blk] = v5;
            partials[ 6 * NBLK + blk] = v6;  partials[ 7 * NBLK + blk] = v7;
            partials[ 8 * NBLK + blk] = v8;  partials[ 9 * NBLK + blk] = v9;
            partials[10 * NBLK + blk] = v10; partials[11 * NBLK + blk] = v11;
        }
    }
}

// ---------------------------------------------------------------------------
// Finalize: one block. Detects mask format, reduces 12 partial arrays, emits.
// ---------------------------------------------------------------------------
__global__ __launch_bounds__(NT) void s2ld_finalize(
    const float* __restrict__ partials,
    const void*  __restrict__ maskp,
    float*       __restrict__ out)
{
    __shared__ float fin[12 * NW];
    __shared__ u32   sbad;

    const int tid  = threadIdx.x;
    const int lane = tid & 63;
    const int wv   = tid >> 6;

    if (tid == 0) sbad = 0u;
    __syncthreads();
    {
        // mask format detection (first 2400 words in-bounds for all layouts)
        u32 bad = 0u;
        const u32* mwp = (const u32*)maskp;
        for (int i = tid; i < 2400; i += NT) {
            u32 w = mwp[i];
            if (w != 0u && w != 1u && w != 0x3f800000u) bad = 1u;
        }
        atomicOr(&sbad, bad);
    }

    for (int k = 0; k < 12; ++k) {
        float s = 0.0f;
        for (int rbl = tid; rbl < NBLK; rbl += NT) s += partials[k * NBLK + rbl];
        #pragma unroll
        for (int off = 32; off; off >>= 1) s += __shfl_xor(s, off);
        if (lane == 0) fin[k * NW + wv] = s;
    }
    __syncthreads();

    if (tid == 0) {
        const int o = (sbad == 0u) ? 0 : 6;   // word-format vs byte-format
        float S[6];
        #pragma unroll
        for (int k = 0; k < 6; ++k) {
            float s = 0.0f;
            #pragma unroll
            for (int w = 0; w < NW; ++w) s += fin[(o + k) * NW + w];
            S[k] = s;
        }
        const float den = fmaxf(S[0], 1.0f);
        const float lm  = S[1] / den;
        out[0] = lm;                              // loc_loss_mean
        out[1] = (S[2] - lm * S[3]) / den;        // rep_loss_mean
        out[2] = 2.0f * S[5] / fmaxf(S[4], 1.0f); // score_loss
    }
}

extern "C" void kernel_launch(void* const* d_in, const int* in_sizes, int n_in,
                              void* d_out, int out_size, void* d_ws, size_t ws_size,
                              hipStream_t stream) {
    const float* w_pt0  = (const float*)d_in[0];
    const float* pt1    = (const float*)d_in[1];
    const void*  maskp  =               d_in[2];
    const float* score0 = (const float*)d_in[3];
    const float* score1 = (const float*)d_in[4];
    // d_in[5] = image1 (zeros) -- unused
    const float* scale0 = (const float*)d_in[6];
    const float* scale1 = (const float*)d_in[7];

    float* partials = (float*)d_ws;   // 12 * 400 * 4 B, fully rewritten

    s2ld_main<<<NBLK, NT, 0, stream>>>(w_pt0, pt1, maskp, score0, score1,
                                       scale0, scale1, partials);
    s2ld_finalize<<<1, NT, 0, stream>>>(partials, maskp, (float*)d_out);
}